// Round 1
// baseline (179.528 us; speedup 1.0000x reference)
//
#include <hip/hip_runtime.h>
#include <cstdint>

#define N_ANCH 8400
#define CBLK 132              // ceil(8400/64)
#define SCORE_THR 0.5f

typedef unsigned long long u64;
typedef unsigned int u32;

// Sort key: ascending sort == (valid score descending, then index ascending,
// invalid last by index ascending) — exactly matches
// argsort(-where(valid, s, -inf)) with stable ties.
__device__ __forceinline__ u64 sort_key(float s, int idx) {
  u32 k32 = (s >= SCORE_THR) ? ~__float_as_uint(s) : 0xFFFFFFFFu;
  return ((u64)k32 << 32) | (u32)idx;
}

__device__ __forceinline__ u64 readlane_u64(u64 v, int l) {
  u32 rlo = (u32)__builtin_amdgcn_readlane((int)(u32)v, l);
  u32 rhi = (u32)__builtin_amdgcn_readlane((int)(u32)(v >> 32), l);
  return ((u64)rhi << 32) | rlo;
}

// One 64-lane wave per anchor: rank = #{keys smaller}, then scatter
// decoded box + score into sorted position.
__global__ void __launch_bounds__(256) rank_kernel(const float* __restrict__ raw,
                                                   float4* __restrict__ sbox,
                                                   float* __restrict__ sscore) {
  #pragma clang fp contract(off)
  int tid = blockIdx.x * 256 + threadIdx.x;
  int row = tid >> 6, lane = tid & 63;
  if (row >= N_ANCH) return;
  float si = raw[4 * N_ANCH + row];
  u64 ki = sort_key(si, row);
  int cnt = 0;
  for (int j = lane; j < N_ANCH; j += 64) {
    float sj = raw[4 * N_ANCH + j];
    cnt += (sort_key(sj, j) < ki) ? 1 : 0;
  }
  #pragma unroll
  for (int d = 1; d < 64; d <<= 1) cnt += __shfl_xor(cnt, d, 64);
  if (lane == 0) {
    float cx = raw[row], cy = raw[N_ANCH + row];
    float w = raw[2 * N_ANCH + row], h = raw[3 * N_ANCH + row];
    float hw = w * 0.5f, hh = h * 0.5f;
    sbox[cnt] = make_float4(cx - hw, cy - hh, cx + hw, cy + hh);
    sscore[cnt] = si;
  }
}

// Suppression bitmask over sorted boxes. 256 threads = 256 rows x 64 cols
// per block; grid (CBLK, 33). mask[i*CBLK+cb] bit jj set iff j=cb*64+jj has
// j>i, j<N, iou(i,j) > 0.5. Skips tiles below the diagonal and tiles with
// all-invalid rows/cols (validity is a prefix in sorted order).
__global__ void __launch_bounds__(256) mask_kernel(const float4* __restrict__ sbox,
                                                   const float* __restrict__ sscore,
                                                   u64* __restrict__ mask) {
  #pragma clang fp contract(off)
  int cb = blockIdx.x;
  int i0 = blockIdx.y * 256;
  if (cb * 64 + 63 < i0) return;
  if (!(sscore[i0] >= SCORE_THR)) return;
  if (!(sscore[cb * 64] >= SCORE_THR)) return;
  int t = threadIdx.x;
  __shared__ float4 cbox[64];
  __shared__ float carea[64];
  int j0 = cb * 64;
  if (t < 64) {
    int j = j0 + t;
    float4 bj = (j < N_ANCH) ? sbox[j] : make_float4(0.f, 0.f, 0.f, 0.f);
    cbox[t] = bj;
    carea[t] = (bj.z - bj.x) * (bj.w - bj.y);
  }
  __syncthreads();
  int i = i0 + t;
  if (i >= N_ANCH || i >= (cb + 1) * 64) return;
  float4 bi = sbox[i];
  float ai = (bi.z - bi.x) * (bi.w - bi.y);
  u64 word = 0;
  for (int jj = 0; jj < 64; ++jj) {
    int jg = j0 + jj;
    if (jg <= i || jg >= N_ANCH) continue;
    float4 bb = cbox[jj];
    float ltx = fmaxf(bi.x, bb.x), lty = fmaxf(bi.y, bb.y);
    float rbx = fminf(bi.z, bb.z), rby = fminf(bi.w, bb.w);
    float wx = fmaxf(rbx - ltx, 0.f), wy = fmaxf(rby - lty, 0.f);
    float inter = wx * wy;
    float uni = (ai + carea[jj]) - inter;      // same op order as reference
    float iou = inter / fmaxf(uni, 1e-9f);     // IEEE div, matches numpy
    if (iou > 0.5f) word |= (1ull << jj);
  }
  mask[(u64)i * CBLK + cb] = word;
}

// 128 rows (one "super-block" = two 64-row words) per sequential iteration.
// 512 threads = 8 waves = (2 col-sets s) x (4 row-quarters q). Iteration T
// scans words b0=2T, b1=2T+1; the word0->word1 dependency is resolved
// IN-REGISTER inside the scan (word0 keepers apply their mask[row][b1] word
// to word1's active set via readlane), so no barrier/LDS round trip between
// the two words. Wave (s,q) then applies rows 16q..16q+15 of BOTH words to
// column-blocks c = 2T+2+64s+lane (c<VB predicated; tile regs v0/v1 loaded
// one iteration ahead). Diagonal mask words are double-buffered and issued
// at the TOP of the iteration (address depends only on T), so they get a
// full iteration (~1us) of latency slack instead of ~400cy. rem4 = 4
// quarter-partial LDS arrays (exclusive (q,c) cells, no atomics). The
// barrier drains LDS ONLY — all global prefetches stay in flight across it.
// Scan runs redundantly in all 8 waves.
__global__ void __launch_bounds__(512, 1) nms_kernel(const float4* __restrict__ sbox,
                                                     const float* __restrict__ sscore,
                                                     const u64* __restrict__ mask,
                                                     float* __restrict__ out) {
  __shared__ u64 keepw[CBLK];
  __shared__ u64 rem4[4][CBLK];
  int tid = threadIdx.x;
  int wave = tid >> 6, lane = tid & 63;
  int s = wave >> 2, q = wave & 3;

  // ---- n_valid via 2-round probe (redundant in every wave — same result)
  float s0 = sscore[lane * 132];                 // 63*132 = 8316 < 8400
  u64 pb = __ballot(s0 >= SCORE_THR);
  int cnt1 = (int)__popcll(pb);
  int n_valid = 0;
  if (cnt1 > 0) {
    int a = (cnt1 - 1) * 132 + 1;                // rows < a known valid
    int i1 = a + 3 * lane;
    float t1 = (i1 + 0 < N_ANCH) ? sscore[i1 + 0] : -1.f;
    float t2 = (i1 + 1 < N_ANCH) ? sscore[i1 + 1] : -1.f;
    float t3 = (i1 + 2 < N_ANCH) ? sscore[i1 + 2] : -1.f;
    u64 q1 = __ballot(t1 >= SCORE_THR);
    u64 q2 = __ballot(t2 >= SCORE_THR);
    u64 q3 = __ballot(t3 >= SCORE_THR);
    n_valid = a + (int)__popcll(q1) + (int)__popcll(q2) + (int)__popcll(q3);
  }
  int VB = (n_valid + 63) >> 6;                  // number of valid 64-blocks
  int NT = (VB + 1) >> 1;                        // number of 128-row super-iters

  for (int b = tid; b < CBLK; b += 512) keepw[b] = 0;
  for (int x = tid; x < 4 * CBLK; x += 512) ((u64*)rem4)[x] = 0;

  u64 v0[16], v1[16];                            // per-wave tile (64 VGPRs)
  auto issue_tiles = [&](int T) {                // tiles consumed at iter T
    int c = 2 * T + 2 + 64 * s + lane;
    bool ok = (c < VB);
    int rb0 = 128 * T + 16 * q;                  // word0 rows (always <8384)
    int rb1 = rb0 + 64;                          // word1 rows
    if (rb1 > N_ANCH - 16) rb1 = N_ANCH - 16;    // clamp (pathological VB=132 only;
                                                 // clamped rows have kws bit 0)
    const u64* p0 = mask + (u64)rb0 * CBLK + c;
    const u64* p1 = mask + (u64)rb1 * CBLK + c;
    #pragma unroll
    for (int i = 0; i < 16; ++i) v0[i] = ok ? p0[(u64)i * CBLK] : 0ull;
    #pragma unroll
    for (int i = 0; i < 16; ++i) v1[i] = ok ? p1[(u64)i * CBLK] : 0ull;
  };

  // Diagonal words, double-buffered. Lane l holds:
  //   A = mask[64*b0+l][b0]  (word0 rows vs word0 cols)
  //   B = mask[64*b0+l][b1]  (word0 rows vs word1 cols)
  //   C = mask[64*b1+l][b1]  (word1 rows vs word1 cols)
  u64 mwA_c = 0, mwB_c = 0, mwC_c = 0;
  u64 mwA_n = 0, mwB_n = 0, mwC_n = 0;
  auto load_diag = [&](int T, u64& A, u64& B, u64& C) {
    int bb0 = 2 * T, bb1 = 2 * T + 1;
    int r0 = bb0 * 64 + lane;                    // always < 8384, in-bounds
    int r1 = bb1 * 64 + lane;
    if (r1 > N_ANCH - 1) r1 = N_ANCH - 1;        // bb1=131 worst case; clamped
                                                 // lanes are invalid rows (act=0)
    bool okb1 = (bb1 < VB);
    A = mask[(u64)r0 * CBLK + bb0];
    B = okb1 ? mask[(u64)r0 * CBLK + bb1] : 0ull;
    C = okb1 ? mask[(u64)r1 * CBLK + bb1] : 0ull;
  };

  if (NT > 0) {
    load_diag(0, mwA_c, mwB_c, mwC_c);
    issue_tiles(0);
  }

  for (int T = 0; T < NT; ++T) {
    int bb0 = 2 * T, bb1 = 2 * T + 1;
    // rotate diag buffers (loads issued a full iteration ago -> no stall),
    // then issue next iteration's diag loads BEFORE the barrier: they stay
    // in flight across it and have a whole iteration to land.
    if (T > 0) { mwA_c = mwA_n; mwB_c = mwB_n; mwC_c = mwC_n; }
    if (T + 1 < NT) load_diag(T + 1, mwA_n, mwB_n, mwC_n);

    // LDS-only drain + barrier: global prefetches stay in flight
    asm volatile("s_waitcnt lgkmcnt(0)\ns_barrier" ::: "memory");

    u64 remb0 = rem4[0][bb0] | rem4[1][bb0] | rem4[2][bb0] | rem4[3][bb0];
    u64 remb1 = rem4[0][bb1] | rem4[1][bb1] | rem4[2][bb1] | rem4[3][bb1];
    int remn0 = n_valid - bb0 * 64;              // >= 1
    int remn1 = remn0 - 64;
    u64 vm0 = (remn0 >= 64) ? ~0ull : ((1ull << remn0) - 1ull);
    u64 vm1 = (remn1 >= 64) ? ~0ull
            : ((remn1 <= 0) ? 0ull : ((1ull << remn1) - 1ull));
    u64 act0 = vm0 & ~remb0;
    u64 act1 = vm1 & ~remb1;

    // ---- scan word0 (ballot fast path; redundant & identical in all waves).
    // sup0 = "suppresses something in THIS super-block" (word0 OR word1):
    // boxes below the first such active box keep and touch nothing.
    u64 a0 = act0, a1 = act1, kw0 = 0, kw1 = 0;
    u64 sup0 = __ballot((((act0 >> lane) & 1ull) != 0ull) &&
                        ((mwA_c | mwB_c) != 0ull));
    while (a0) {
      u64 as = a0 & sup0;
      if (as == 0ull) { kw0 |= a0; break; }
      int f = (int)__builtin_ctzll(as);
      u64 below = a0 & ((1ull << f) - 1ull);
      kw0 |= below | (1ull << f);
      u64 ml0 = readlane_u64(mwA_c, f);
      u64 ml1 = readlane_u64(mwB_c, f);
      a0 &= ~(below | (1ull << f) | ml0);
      a1 &= ~ml1;                                // word0 keeper suppresses word1
    }
    // ---- scan word1 (a1 already carries word0 keepers' suppression)
    u64 sup1 = __ballot((((act1 >> lane) & 1ull) != 0ull) && (mwC_c != 0ull));
    while (a1) {
      u64 as = a1 & sup1;
      if (as == 0ull) { kw1 |= a1; break; }
      int f = (int)__builtin_ctzll(as);
      u64 below = a1 & ((1ull << f) - 1ull);
      kw1 |= below | (1ull << f);
      u64 ml = readlane_u64(mwC_c, f);
      a1 &= ~(below | (1ull << f) | ml);
    }
    if (tid == 0) { keepw[bb0] = kw0; keepw[bb1] = kw1; }

    // scalarized keep words
    u32 k0lo = (u32)__builtin_amdgcn_readfirstlane((int)(u32)kw0);
    u32 k0hi = (u32)__builtin_amdgcn_readfirstlane((int)(u32)(kw0 >> 32));
    u32 k1lo = (u32)__builtin_amdgcn_readfirstlane((int)(u32)kw1);
    u32 k1hi = (u32)__builtin_amdgcn_readfirstlane((int)(u32)(kw1 >> 32));
    u64 kws0 = ((u64)k0hi << 32) | k0lo;
    u64 kws1 = ((u64)k1hi << 32) | k1lo;

    // ---- consume tiles (loads issued last iteration): masked OR + LDS RMW
    {
      u64 acc = 0;
      #pragma unroll
      for (int i = 0; i < 16; ++i) {
        u64 sm0 = (u64)0 - ((kws0 >> (16 * q + i)) & 1ull);
        u64 sm1 = (u64)0 - ((kws1 >> (16 * q + i)) & 1ull);
        acc |= (v0[i] & sm0) | (v1[i] & sm1);
      }
      int c = 2 * T + 2 + 64 * s + lane;
      if (c < VB) rem4[q][c] |= acc;             // exclusive (q,c) cell
    }

    // ---- issue tiles for next iteration (regs just consumed)
    if (T + 1 < NT) issue_tiles(T + 1);

    // ---- rare far window [2T+130, VB) — only when VB >= 131 (never at
    // VB~66); covers columns beyond the 128-wide sliding window at T=0.
    if (2 * T + 130 < VB && s == 1) {
      int c2 = 2 * T + 130 + lane;
      if (c2 < VB) {
        int rb0 = 128 * T + 16 * q;
        int rb1 = rb0 + 64;
        if (rb1 > N_ANCH - 16) rb1 = N_ANCH - 16;
        const u64* p0 = mask + (u64)rb0 * CBLK + c2;
        const u64* p1 = mask + (u64)rb1 * CBLK + c2;
        u64 acc2 = 0;
        #pragma unroll
        for (int i = 0; i < 16; ++i) {
          u64 sm0 = (u64)0 - ((kws0 >> (16 * q + i)) & 1ull);
          u64 sm1 = (u64)0 - ((kws1 >> (16 * q + i)) & 1ull);
          acc2 |= (p0[(u64)i * CBLK] & sm0) | (p1[(u64)i * CBLK] & sm1);
        }
        rem4[q][c2] |= acc2;                     // disjoint from c (> 2T+129)
      }
    }
  }
  __syncthreads();

  // ---- fused masked output (512 threads)
  for (int r2 = tid; r2 < N_ANCH; r2 += 512) {
    u64 kv = keepw[r2 >> 6];
    bool kp = (kv >> (r2 & 63)) & 1ull;
    float4 b4 = sbox[r2];
    float sc = sscore[r2];
    float* o = out + r2 * 5;
    o[0] = kp ? b4.x : 0.f;
    o[1] = kp ? b4.y : 0.f;
    o[2] = kp ? b4.z : 0.f;
    o[3] = kp ? b4.w : 0.f;
    o[4] = kp ? sc : 0.f;
  }
}

extern "C" void kernel_launch(void* const* d_in, const int* in_sizes, int n_in,
                              void* d_out, int out_size, void* d_ws, size_t ws_size,
                              hipStream_t stream) {
  const float* raw = (const float*)d_in[0];
  float* out = (float*)d_out;
  char* ws = (char*)d_ws;
  // ws layout: sbox (8448*16 B) | sscore (8448*4 B) | mask (8400*132*8 B) ≈ 9.04 MB
  float4* sbox = (float4*)ws;
  float* sscore = (float*)(ws + 8448 * 16);
  u64* mask = (u64*)(ws + 8448 * 16 + 8448 * 4);

  rank_kernel<<<2100, 256, 0, stream>>>(raw, sbox, sscore);
  mask_kernel<<<dim3(CBLK, 33), 256, 0, stream>>>(sbox, sscore, mask);
  nms_kernel<<<1, 512, 0, stream>>>(sbox, sscore, mask, out);
}

// Round 2
// 179.270 us; speedup vs baseline: 1.0014x; 1.0014x over previous
//
#include <hip/hip_runtime.h>
#include <cstdint>

#define N_ANCH 8400
#define CBLK 132              // ceil(8400/64)
#define SCORE_THR 0.5f

typedef unsigned long long u64;
typedef unsigned int u32;

// Sort key: ascending sort == (valid score descending, then index ascending,
// invalid last by index ascending) — exactly matches
// argsort(-where(valid, s, -inf)) with stable ties.
__device__ __forceinline__ u64 sort_key(float s, int idx) {
  u32 k32 = (s >= SCORE_THR) ? ~__float_as_uint(s) : 0xFFFFFFFFu;
  return ((u64)k32 << 32) | (u32)idx;
}

__device__ __forceinline__ u64 readlane_u64(u64 v, int l) {
  u32 rlo = (u32)__builtin_amdgcn_readlane((int)(u32)v, l);
  u32 rhi = (u32)__builtin_amdgcn_readlane((int)(u32)(v >> 32), l);
  return ((u64)rhi << 32) | rlo;
}

// Force a wave-uniform u64 into SGPRs (scalarize the scan state).
__device__ __forceinline__ u64 rfl64(u64 v) {
  u32 lo = (u32)__builtin_amdgcn_readfirstlane((int)(u32)v);
  u32 hi = (u32)__builtin_amdgcn_readfirstlane((int)(u32)(v >> 32));
  return ((u64)hi << 32) | lo;
}

// One 64-lane wave per anchor: rank = #{keys smaller}, then scatter
// decoded box + score into sorted position.
__global__ void __launch_bounds__(256) rank_kernel(const float* __restrict__ raw,
                                                   float4* __restrict__ sbox,
                                                   float* __restrict__ sscore) {
  #pragma clang fp contract(off)
  int tid = blockIdx.x * 256 + threadIdx.x;
  int row = tid >> 6, lane = tid & 63;
  if (row >= N_ANCH) return;
  float si = raw[4 * N_ANCH + row];
  u64 ki = sort_key(si, row);
  int cnt = 0;
  for (int j = lane; j < N_ANCH; j += 64) {
    float sj = raw[4 * N_ANCH + j];
    cnt += (sort_key(sj, j) < ki) ? 1 : 0;
  }
  #pragma unroll
  for (int d = 1; d < 64; d <<= 1) cnt += __shfl_xor(cnt, d, 64);
  if (lane == 0) {
    float cx = raw[row], cy = raw[N_ANCH + row];
    float w = raw[2 * N_ANCH + row], h = raw[3 * N_ANCH + row];
    float hw = w * 0.5f, hh = h * 0.5f;
    sbox[cnt] = make_float4(cx - hw, cy - hh, cx + hw, cy + hh);
    sscore[cnt] = si;
  }
}

// Suppression bitmask over sorted boxes. 256 threads = 256 rows x 64 cols
// per block; grid (CBLK, 33). mask[i*CBLK+cb] bit jj set iff j=cb*64+jj has
// j>i, j<N, iou(i,j) > 0.5. Skips tiles below the diagonal and tiles with
// all-invalid rows/cols (validity is a prefix in sorted order).
__global__ void __launch_bounds__(256) mask_kernel(const float4* __restrict__ sbox,
                                                   const float* __restrict__ sscore,
                                                   u64* __restrict__ mask) {
  #pragma clang fp contract(off)
  int cb = blockIdx.x;
  int i0 = blockIdx.y * 256;
  if (cb * 64 + 63 < i0) return;
  if (!(sscore[i0] >= SCORE_THR)) return;
  if (!(sscore[cb * 64] >= SCORE_THR)) return;
  int t = threadIdx.x;
  __shared__ float4 cbox[64];
  __shared__ float carea[64];
  int j0 = cb * 64;
  if (t < 64) {
    int j = j0 + t;
    float4 bj = (j < N_ANCH) ? sbox[j] : make_float4(0.f, 0.f, 0.f, 0.f);
    cbox[t] = bj;
    carea[t] = (bj.z - bj.x) * (bj.w - bj.y);
  }
  __syncthreads();
  int i = i0 + t;
  if (i >= N_ANCH || i >= (cb + 1) * 64) return;
  float4 bi = sbox[i];
  float ai = (bi.z - bi.x) * (bi.w - bi.y);
  u64 word = 0;
  for (int jj = 0; jj < 64; ++jj) {
    int jg = j0 + jj;
    if (jg <= i || jg >= N_ANCH) continue;
    float4 bb = cbox[jj];
    float ltx = fmaxf(bi.x, bb.x), lty = fmaxf(bi.y, bb.y);
    float rbx = fminf(bi.z, bb.z), rby = fminf(bi.w, bb.w);
    float wx = fmaxf(rbx - ltx, 0.f), wy = fmaxf(rby - lty, 0.f);
    float inter = wx * wy;
    float uni = (ai + carea[jj]) - inter;      // same op order as reference
    float iou = inter / fmaxf(uni, 1e-9f);     // IEEE div, matches numpy
    if (iou > 0.5f) word |= (1ull << jj);
  }
  mask[(u64)i * CBLK + cb] = word;
}

// 128 rows (two 64-row words) per sequential iteration; 512 threads = 8
// waves = (2 col-sets s) x (4 row-quarters q).
//
// The greedy scan (the serial dependency chain, ~80-90% of runtime in prior
// versions) is now:
//   (a) SCALARIZED — rem/act/sup/kw state is forced into SGPRs (rfl64 on
//       LDS-sourced words; ballots are already SGPR), and the loop is the
//       minimal chain s_and -> s_ff1 -> v_readlane -> s_or -> s_andn2.
//       Keep-word bookkeeping (bit = as & -as, k |= bit) runs OFF the chain;
//       kw = a_final | keepers (same set as the old below-accumulation).
//   (b) DEDUPLICATED — only wave 0 runs the scan (the CU has ONE scalar unit
//       shared by 4 SIMDs; 8 redundant SALU chains contend ~8x). Keep words
//       are published via LDS + a second barrier (~200cy/iter — barriers
//       were measured to be ~free here).
//
// Tiles v0/v1 are prefetched one iteration ahead; diag words double-buffered
// and issued at the top of the iteration (all waves load them to keep the
// compiler's vmcnt bookkeeping uniform; only wave 0 consumes them). Barriers
// drain LDS ONLY — global prefetches stay in flight across them. rem4 = 4
// quarter-partial LDS arrays (exclusive (q,c) cells, no atomics).
__global__ void __launch_bounds__(512, 1) nms_kernel(const float4* __restrict__ sbox,
                                                     const float* __restrict__ sscore,
                                                     const u64* __restrict__ mask,
                                                     float* __restrict__ out) {
  __shared__ u64 keepw[CBLK];
  __shared__ u64 rem4[4][CBLK];
  int tid = threadIdx.x;
  int wave = tid >> 6, lane = tid & 63;
  int s = wave >> 2, q = wave & 3;

  // ---- n_valid via 2-round probe (redundant in every wave — same result)
  float s0 = sscore[lane * 132];                 // 63*132 = 8316 < 8400
  u64 pb = __ballot(s0 >= SCORE_THR);
  int cnt1 = (int)__popcll(pb);
  int n_valid = 0;
  if (cnt1 > 0) {
    int a = (cnt1 - 1) * 132 + 1;                // rows < a known valid
    int i1 = a + 3 * lane;
    float t1 = (i1 + 0 < N_ANCH) ? sscore[i1 + 0] : -1.f;
    float t2 = (i1 + 1 < N_ANCH) ? sscore[i1 + 1] : -1.f;
    float t3 = (i1 + 2 < N_ANCH) ? sscore[i1 + 2] : -1.f;
    u64 q1 = __ballot(t1 >= SCORE_THR);
    u64 q2 = __ballot(t2 >= SCORE_THR);
    u64 q3 = __ballot(t3 >= SCORE_THR);
    n_valid = a + (int)__popcll(q1) + (int)__popcll(q2) + (int)__popcll(q3);
  }
  int VB = (n_valid + 63) >> 6;                  // number of valid 64-blocks
  int NT = (VB + 1) >> 1;                        // number of 128-row super-iters

  for (int b = tid; b < CBLK; b += 512) keepw[b] = 0;
  for (int x = tid; x < 4 * CBLK; x += 512) ((u64*)rem4)[x] = 0;

  u64 v0[16], v1[16];                            // per-wave tile (64 VGPRs)
  auto issue_tiles = [&](int T) {                // tiles consumed at iter T
    int c = 2 * T + 2 + 64 * s + lane;
    bool ok = (c < VB);
    int rb0 = 128 * T + 16 * q;                  // word0 rows (always <8384)
    int rb1 = rb0 + 64;                          // word1 rows
    if (rb1 > N_ANCH - 16) rb1 = N_ANCH - 16;    // clamp (pathological VB=132 only;
                                                 // clamped rows have kws bit 0)
    const u64* p0 = mask + (u64)rb0 * CBLK + c;
    const u64* p1 = mask + (u64)rb1 * CBLK + c;
    #pragma unroll
    for (int i = 0; i < 16; ++i) v0[i] = ok ? p0[(u64)i * CBLK] : 0ull;
    #pragma unroll
    for (int i = 0; i < 16; ++i) v1[i] = ok ? p1[(u64)i * CBLK] : 0ull;
  };

  // Diagonal words, double-buffered. Lane l holds:
  //   A = mask[64*b0+l][b0]  (word0 rows vs word0 cols)
  //   B = mask[64*b0+l][b1]  (word0 rows vs word1 cols)
  //   C = mask[64*b1+l][b1]  (word1 rows vs word1 cols)
  u64 mwA_c = 0, mwB_c = 0, mwC_c = 0;
  u64 mwA_n = 0, mwB_n = 0, mwC_n = 0;
  auto load_diag = [&](int T, u64& A, u64& B, u64& C) {
    int bb0 = 2 * T, bb1 = 2 * T + 1;
    int r0 = bb0 * 64 + lane;                    // always < 8384, in-bounds
    int r1 = bb1 * 64 + lane;
    if (r1 > N_ANCH - 1) r1 = N_ANCH - 1;        // bb1=131 worst case; clamped
                                                 // lanes are invalid rows (act=0)
    bool okb1 = (bb1 < VB);
    A = mask[(u64)r0 * CBLK + bb0];
    B = okb1 ? mask[(u64)r0 * CBLK + bb1] : 0ull;
    C = okb1 ? mask[(u64)r1 * CBLK + bb1] : 0ull;
  };

  if (NT > 0) {
    load_diag(0, mwA_c, mwB_c, mwC_c);
    issue_tiles(0);
  }

  for (int T = 0; T < NT; ++T) {
    int bb0 = 2 * T, bb1 = 2 * T + 1;
    // rotate diag buffers (loads issued a full iteration ago -> no stall),
    // then issue next iteration's diag loads BEFORE the barrier: they stay
    // in flight across it and have a whole iteration to land.
    if (T > 0) { mwA_c = mwA_n; mwB_c = mwB_n; mwC_c = mwC_n; }
    if (T + 1 < NT) load_diag(T + 1, mwA_n, mwB_n, mwC_n);

    // barrier #1: rem4 RMWs from iter T-1 visible. LDS-only drain; global
    // prefetches stay in flight.
    asm volatile("s_waitcnt lgkmcnt(0)\ns_barrier" ::: "memory");

    if (wave == 0) {
      // ---- scalarized greedy scan (wave 0 only)
      u64 remb0 = rfl64(rem4[0][bb0] | rem4[1][bb0] | rem4[2][bb0] | rem4[3][bb0]);
      u64 remb1 = rfl64(rem4[0][bb1] | rem4[1][bb1] | rem4[2][bb1] | rem4[3][bb1]);
      int remn0 = n_valid - bb0 * 64;            // >= 1
      int remn1 = remn0 - 64;
      u64 vm0 = (remn0 >= 64) ? ~0ull : ((1ull << remn0) - 1ull);
      u64 vm1 = (remn1 >= 64) ? ~0ull
              : ((remn1 <= 0) ? 0ull : ((1ull << remn1) - 1ull));
      u64 act0 = vm0 & ~remb0;                   // SGPR
      u64 act1 = vm1 & ~remb1;                   // SGPR

      // word0: sup0 = active boxes that statically suppress something in
      // this super-block (word0 via A, or word1 via B).
      u64 sup0 = __ballot((((act0 >> lane) & 1ull) != 0ull) &&
                          ((mwA_c | mwB_c) != 0ull));
      u64 a0v = act0, a1v = act1, k0 = 0, as;
      while ((as = a0v & sup0) != 0ull) {
        int f = (int)__builtin_ctzll(as);        // chain: and -> ff1
        u64 bit = as & (0ull - as);              // off-chain (parallel)
        u64 ml0 = readlane_u64(mwA_c, f);        // -> readlane
        u64 ml1 = readlane_u64(mwB_c, f);
        k0 |= bit;
        a0v &= ~(bit | ml0);                     // -> or -> andn2 -> loop
        a1v &= ~ml1;                             // off the a0 chain
      }
      u64 kw0 = a0v | k0;                        // survivors + keepers

      // word1 (a1v already carries word0 keepers' suppression via B)
      u64 sup1 = __ballot((((act1 >> lane) & 1ull) != 0ull) && (mwC_c != 0ull));
      u64 k1 = 0;
      while ((as = a1v & sup1) != 0ull) {
        int f = (int)__builtin_ctzll(as);
        u64 bit = as & (0ull - as);
        u64 ml = readlane_u64(mwC_c, f);
        k1 |= bit;
        a1v &= ~(bit | ml);
      }
      u64 kw1 = a1v | k1;

      if (lane == 0) { keepw[bb0] = kw0; keepw[bb1] = kw1; }
    }

    // barrier #2: publish keep words (lgkmcnt(0) drains wave 0's ds_write)
    asm volatile("s_waitcnt lgkmcnt(0)\ns_barrier" ::: "memory");

    u64 kws0 = rfl64(keepw[bb0]);                // broadcast read, same addr
    u64 kws1 = rfl64(keepw[bb1]);

    // ---- consume tiles (loads issued last iteration): masked OR + LDS RMW
    {
      u64 acc = 0;
      #pragma unroll
      for (int i = 0; i < 16; ++i) {
        u64 sm0 = (u64)0 - ((kws0 >> (16 * q + i)) & 1ull);
        u64 sm1 = (u64)0 - ((kws1 >> (16 * q + i)) & 1ull);
        acc |= (v0[i] & sm0) | (v1[i] & sm1);
      }
      int c = 2 * T + 2 + 64 * s + lane;
      if (c < VB) rem4[q][c] |= acc;             // exclusive (q,c) cell
    }

    // ---- issue tiles for next iteration (regs just consumed)
    if (T + 1 < NT) issue_tiles(T + 1);

    // ---- rare far window [2T+130, VB) — only when VB >= 131 (never at
    // VB~66); covers columns beyond the 128-wide sliding window at T=0.
    if (2 * T + 130 < VB && s == 1) {
      int c2 = 2 * T + 130 + lane;
      if (c2 < VB) {
        int rb0 = 128 * T + 16 * q;
        int rb1 = rb0 + 64;
        if (rb1 > N_ANCH - 16) rb1 = N_ANCH - 16;
        const u64* p0 = mask + (u64)rb0 * CBLK + c2;
        const u64* p1 = mask + (u64)rb1 * CBLK + c2;
        u64 acc2 = 0;
        #pragma unroll
        for (int i = 0; i < 16; ++i) {
          u64 sm0 = (u64)0 - ((kws0 >> (16 * q + i)) & 1ull);
          u64 sm1 = (u64)0 - ((kws1 >> (16 * q + i)) & 1ull);
          acc2 |= (p0[(u64)i * CBLK] & sm0) | (p1[(u64)i * CBLK] & sm1);
        }
        rem4[q][c2] |= acc2;                     // disjoint from c (> 2T+129)
      }
    }
  }
  __syncthreads();

  // ---- fused masked output (512 threads)
  for (int r2 = tid; r2 < N_ANCH; r2 += 512) {
    u64 kv = keepw[r2 >> 6];
    bool kp = (kv >> (r2 & 63)) & 1ull;
    float4 b4 = sbox[r2];
    float sc = sscore[r2];
    float* o = out + r2 * 5;
    o[0] = kp ? b4.x : 0.f;
    o[1] = kp ? b4.y : 0.f;
    o[2] = kp ? b4.z : 0.f;
    o[3] = kp ? b4.w : 0.f;
    o[4] = kp ? sc : 0.f;
  }
}

extern "C" void kernel_launch(void* const* d_in, const int* in_sizes, int n_in,
                              void* d_out, int out_size, void* d_ws, size_t ws_size,
                              hipStream_t stream) {
  const float* raw = (const float*)d_in[0];
  float* out = (float*)d_out;
  char* ws = (char*)d_ws;
  // ws layout: sbox (8448*16 B) | sscore (8448*4 B) | mask (8400*132*8 B) ≈ 9.04 MB
  float4* sbox = (float4*)ws;
  float* sscore = (float*)(ws + 8448 * 16);
  u64* mask = (u64*)(ws + 8448 * 16 + 8448 * 4);

  rank_kernel<<<2100, 256, 0, stream>>>(raw, sbox, sscore);
  mask_kernel<<<dim3(CBLK, 33), 256, 0, stream>>>(sbox, sscore, mask);
  nms_kernel<<<1, 512, 0, stream>>>(sbox, sscore, mask, out);
}

// Round 3
// 159.426 us; speedup vs baseline: 1.1261x; 1.1245x over previous
//
#include <hip/hip_runtime.h>
#include <cstdint>

#define N_ANCH 8400
#define CBLK 132              // ceil(8400/64)
#define SCORE_THR 0.5f

typedef unsigned long long u64;
typedef unsigned int u32;

// Sort key: ascending sort == (valid score descending, then index ascending,
// invalid last by index ascending) — exactly matches
// argsort(-where(valid, s, -inf)) with stable ties.
__device__ __forceinline__ u64 sort_key(float s, int idx) {
  u32 k32 = (s >= SCORE_THR) ? ~__float_as_uint(s) : 0xFFFFFFFFu;
  return ((u64)k32 << 32) | (u32)idx;
}

__device__ __forceinline__ u64 readlane_u64(u64 v, int l) {
  u32 rlo = (u32)__builtin_amdgcn_readlane((int)(u32)v, l);
  u32 rhi = (u32)__builtin_amdgcn_readlane((int)(u32)(v >> 32), l);
  return ((u64)rhi << 32) | rlo;
}

// Force a wave-uniform u64 into SGPRs (scalarize the scan state).
__device__ __forceinline__ u64 rfl64(u64 v) {
  u32 lo = (u32)__builtin_amdgcn_readfirstlane((int)(u32)v);
  u32 hi = (u32)__builtin_amdgcn_readfirstlane((int)(u32)(v >> 32));
  return ((u64)hi << 32) | lo;
}

// One 64-lane wave per anchor: rank = #{keys smaller}, then scatter
// decoded box + score into sorted position.
__global__ void __launch_bounds__(256) rank_kernel(const float* __restrict__ raw,
                                                   float4* __restrict__ sbox,
                                                   float* __restrict__ sscore) {
  #pragma clang fp contract(off)
  int tid = blockIdx.x * 256 + threadIdx.x;
  int row = tid >> 6, lane = tid & 63;
  if (row >= N_ANCH) return;
  float si = raw[4 * N_ANCH + row];
  u64 ki = sort_key(si, row);
  int cnt = 0;
  for (int j = lane; j < N_ANCH; j += 64) {
    float sj = raw[4 * N_ANCH + j];
    cnt += (sort_key(sj, j) < ki) ? 1 : 0;
  }
  #pragma unroll
  for (int d = 1; d < 64; d <<= 1) cnt += __shfl_xor(cnt, d, 64);
  if (lane == 0) {
    float cx = raw[row], cy = raw[N_ANCH + row];
    float w = raw[2 * N_ANCH + row], h = raw[3 * N_ANCH + row];
    float hw = w * 0.5f, hh = h * 0.5f;
    sbox[cnt] = make_float4(cx - hw, cy - hh, cx + hw, cy + hh);
    sscore[cnt] = si;
  }
}

// Suppression bitmask over sorted boxes. 256 threads = 256 rows x 64 cols
// per block; grid (CBLK, 33). mask[i*CBLK+cb] bit jj set iff j=cb*64+jj has
// j>i, j<N, iou(i,j) > 0.5. Skips tiles below the diagonal and tiles with
// all-invalid rows/cols (validity is a prefix in sorted order).
__global__ void __launch_bounds__(256) mask_kernel(const float4* __restrict__ sbox,
                                                   const float* __restrict__ sscore,
                                                   u64* __restrict__ mask) {
  #pragma clang fp contract(off)
  int cb = blockIdx.x;
  int i0 = blockIdx.y * 256;
  if (cb * 64 + 63 < i0) return;
  if (!(sscore[i0] >= SCORE_THR)) return;
  if (!(sscore[cb * 64] >= SCORE_THR)) return;
  int t = threadIdx.x;
  __shared__ float4 cbox[64];
  __shared__ float carea[64];
  int j0 = cb * 64;
  if (t < 64) {
    int j = j0 + t;
    float4 bj = (j < N_ANCH) ? sbox[j] : make_float4(0.f, 0.f, 0.f, 0.f);
    cbox[t] = bj;
    carea[t] = (bj.z - bj.x) * (bj.w - bj.y);
  }
  __syncthreads();
  int i = i0 + t;
  if (i >= N_ANCH || i >= (cb + 1) * 64) return;
  float4 bi = sbox[i];
  float ai = (bi.z - bi.x) * (bi.w - bi.y);
  u64 word = 0;
  for (int jj = 0; jj < 64; ++jj) {
    int jg = j0 + jj;
    if (jg <= i || jg >= N_ANCH) continue;
    float4 bb = cbox[jj];
    float ltx = fmaxf(bi.x, bb.x), lty = fmaxf(bi.y, bb.y);
    float rbx = fminf(bi.z, bb.z), rby = fminf(bi.w, bb.w);
    float wx = fmaxf(rbx - ltx, 0.f), wy = fmaxf(rby - lty, 0.f);
    float inter = wx * wy;
    float uni = (ai + carea[jj]) - inter;      // same op order as reference
    float iou = inter / fmaxf(uni, 1e-9f);     // IEEE div, matches numpy
    if (iou > 0.5f) word |= (1ull << jj);
  }
  mask[(u64)i * CBLK + cb] = word;
}

// PIPELINED NMS: 128 rows (words b0=2T, b1=2T+1) per iteration, ONE barrier
// per iteration. Wave 0 scans iteration T while waves 1-7 concurrently apply
// iteration T-1's keep-words (read from LDS post-barrier) to columns
// [2T+2, 2T+130) — scan and consume fully overlap.
//
// The schedule gap (words 2T-2,2T-1 can no longer reach cols 2T,2T+1 via the
// LDS consume in time) is closed by wave 0 itself: after computing kw, it
// OR-reduces the two adjacent mask columns (D/E words, prefetched like the
// diagonal) over keeper lanes with a 6-step shfl_xor butterfly and carries
// the result in REGISTERS across the barrier into the next scan's rem.
//
// Coverage: consume of words 2u,2u+1 (at iter u+1) spans cols [2u+4, 2u+132)
// — max distance 131 exactly covers VB <= 132, so the old far-window special
// case is gone. Cols 2u+2,2u+3 come from wave0's carry. No races: wave0
// reads rem7[*][2T,2T+1] while others write cols >= 2T+2; wave0 writes
// keepw[2T,2T+1] while others read keepw[2T-2,2T-1].
//
// rem7 = 7 per-wave partial arrays (exclusive cells, no atomics). Barriers
// drain LDS ONLY (lgkmcnt) — all global prefetches stay in flight across.
__global__ void __launch_bounds__(512, 1) nms_kernel(const float4* __restrict__ sbox,
                                                     const float* __restrict__ sscore,
                                                     const u64* __restrict__ mask,
                                                     float* __restrict__ out) {
  __shared__ u64 keepw[CBLK];
  __shared__ u64 rem7[7][CBLK];
  int tid = threadIdx.x;
  int wave = tid >> 6, lane = tid & 63;

  // ---- n_valid via 2-round probe (redundant in every wave — same result)
  float s0 = sscore[lane * 132];                 // 63*132 = 8316 < 8400
  u64 pb = __ballot(s0 >= SCORE_THR);
  int cnt1 = (int)__popcll(pb);
  int n_valid = 0;
  if (cnt1 > 0) {
    int a = (cnt1 - 1) * 132 + 1;                // rows < a known valid
    int i1 = a + 3 * lane;
    float t1 = (i1 + 0 < N_ANCH) ? sscore[i1 + 0] : -1.f;
    float t2 = (i1 + 1 < N_ANCH) ? sscore[i1 + 1] : -1.f;
    float t3 = (i1 + 2 < N_ANCH) ? sscore[i1 + 2] : -1.f;
    u64 q1 = __ballot(t1 >= SCORE_THR);
    u64 q2 = __ballot(t2 >= SCORE_THR);
    u64 q3 = __ballot(t3 >= SCORE_THR);
    n_valid = a + (int)__popcll(q1) + (int)__popcll(q2) + (int)__popcll(q3);
  }
  int VB = (n_valid + 63) >> 6;                  // number of valid 64-blocks
  int NT = (VB + 1) >> 1;                        // 128-row iterations

  for (int b = tid; b < CBLK; b += 512) keepw[b] = 0;
  for (int x = tid; x < 7 * CBLK; x += 512) ((u64*)rem7)[x] = 0;

  // ---- consume-wave state (waves 1..7): rows split 19,19,19,19,19,19,14
  int rs = (wave - 1) * 19;                      // row start within 128-pair
  int nr = 128 - rs; if (nr > 19) nr = 19;       // rows this wave owns
  u64 tl[19], th[19];                            // tile: cols cL / cL+64
  auto issue_tiles = [&](int u) {                // words 2u,2u+1 -> iter u+1
    int cL = 2 * u + 4 + lane;
    int cH = cL + 64;
    bool okL = (cL < VB), okH = (cH < VB);
    // rows 128u+rs .. +18: u <= NT-2 <= 64 -> row <= 8324 < 8400, in-bounds
    const u64* pr = mask + (u64)(128 * u + rs) * CBLK;
    #pragma unroll
    for (int r = 0; r < 19; ++r) {
      bool rok = (r < nr);
      tl[r] = (rok && okL) ? pr[(u64)r * CBLK + cL] : 0ull;
      th[r] = (rok && okH) ? pr[(u64)r * CBLK + cH] : 0ull;
    }
  };

  // ---- wave-0 state: diag A/B/C + adjacent-col D/E words, double-buffered.
  // Lane l: A=mask[64b0+l][b0]  B=mask[64b0+l][b1]  C=mask[64b1+l][b1]
  //         D0=mask[64b0+l][b0+2] D1=mask[64b0+l][b0+3]
  //         E0=mask[64b1+l][b0+2] E1=mask[64b1+l][b0+3]
  u64 A_c=0,B_c=0,C_c=0,D0_c=0,D1_c=0,E0_c=0,E1_c=0;
  u64 A_n=0,B_n=0,C_n=0,D0_n=0,D1_n=0,E0_n=0,E1_n=0;
  auto load_w0 = [&](int T, u64&A,u64&B,u64&C,u64&D0,u64&D1,u64&E0,u64&E1) {
    int b0 = 2 * T, b1 = 2 * T + 1;
    int r0 = b0 * 64 + lane;                     // b0<=130 -> r0<=8383, safe
    int r1 = b1 * 64 + lane;
    if (r1 > N_ANCH - 1) r1 = N_ANCH - 1;        // b1=131 tail; clamped lanes
                                                 // have keep-bit 0 (act=0)
    bool ok1 = (b1 < VB);
    bool ok2 = (b0 + 2 < VB);
    bool ok3 = (b0 + 3 < VB);
    const u64* p0 = mask + (u64)r0 * CBLK;
    const u64* p1 = mask + (u64)r1 * CBLK;
    A  = p0[b0];
    B  = ok1 ? p0[b1] : 0ull;
    C  = ok1 ? p1[b1] : 0ull;
    D0 = ok2 ? p0[b0 + 2] : 0ull;
    D1 = ok3 ? p0[b0 + 3] : 0ull;
    E0 = (ok1 && ok2) ? p1[b0 + 2] : 0ull;
    E1 = (ok1 && ok3) ? p1[b0 + 3] : 0ull;
  };

  u64 carry0 = 0, carry1 = 0;                    // words b0-2,b0-1 -> cols b0,b1

  if (wave == 0 && NT > 0) load_w0(0, A_c,B_c,C_c,D0_c,D1_c,E0_c,E1_c);

  for (int T = 0; T < NT; ++T) {
    // one barrier per iteration; LDS-only drain — global loads stay in flight
    asm volatile("s_waitcnt lgkmcnt(0)\ns_barrier" ::: "memory");

    if (wave == 0) {
      // rotate double buffer; issue next iteration's 7 loads immediately
      if (T > 0) { A_c=A_n; B_c=B_n; C_c=C_n; D0_c=D0_n; D1_c=D1_n; E0_c=E0_n; E1_c=E1_n; }
      if (T + 1 < NT) load_w0(T + 1, A_n,B_n,C_n,D0_n,D1_n,E0_n,E1_n);

      int b0 = 2 * T, b1 = 2 * T + 1;
      // gather rem: LDS has words <= b0-3 (consumed by iter T-1); carry has
      // words b0-2,b0-1. Broadcast reads, no conflicts.
      u64 r0v = carry0, r1v = carry1;
      #pragma unroll
      for (int j = 0; j < 7; ++j) { r0v |= rem7[j][b0]; r1v |= rem7[j][b1]; }
      u64 remb0 = rfl64(r0v);
      u64 remb1 = rfl64(r1v);
      int remn0 = n_valid - b0 * 64;             // >= 1
      int remn1 = remn0 - 64;
      u64 vm0 = (remn0 >= 64) ? ~0ull : ((1ull << remn0) - 1ull);
      u64 vm1 = (remn1 >= 64) ? ~0ull
              : ((remn1 <= 0) ? 0ull : ((1ull << remn1) - 1ull));
      u64 act0 = vm0 & ~remb0;                   // SGPR
      u64 act1 = vm1 & ~remb1;                   // SGPR

      // ---- scalarized greedy scan (chain: s_and -> s_ff1 -> readlane -> andn2)
      u64 sup0 = __ballot((((act0 >> lane) & 1ull) != 0ull) &&
                          ((A_c | B_c) != 0ull));
      u64 a0v = act0, a1v = act1, k0 = 0, as;
      while ((as = a0v & sup0) != 0ull) {
        int f = (int)__builtin_ctzll(as);
        u64 bit = as & (0ull - as);              // off-chain
        u64 ml0 = readlane_u64(A_c, f);
        u64 ml1 = readlane_u64(B_c, f);
        k0 |= bit;
        a0v &= ~(bit | ml0);
        a1v &= ~ml1;                             // word0 keeper hits word1
      }
      u64 kw0 = a0v | k0;                        // survivors + keepers

      u64 sup1 = __ballot((((act1 >> lane) & 1ull) != 0ull) && (C_c != 0ull));
      u64 k1 = 0;
      while ((as = a1v & sup1) != 0ull) {
        int f = (int)__builtin_ctzll(as);
        u64 bit = as & (0ull - as);
        u64 ml = readlane_u64(C_c, f);
        k1 |= bit;
        a1v &= ~(bit | ml);
      }
      u64 kw1 = a1v | k1;

      if (lane == 0) { keepw[b0] = kw0; keepw[b1] = kw1; }

      // ---- carry reduce: contribution of words b0,b1 to cols b0+2,b0+3.
      // Butterfly OR over keeper lanes (covers keepers NOT in sup too).
      u64 kb0 = (kw0 >> lane) & 1ull;            // per-lane keep predicate
      u64 kb1 = (kw1 >> lane) & 1ull;
      u64 x0 = (kb0 ? D0_c : 0ull) | (kb1 ? E0_c : 0ull);
      u64 x1 = (kb0 ? D1_c : 0ull) | (kb1 ? E1_c : 0ull);
      #pragma unroll
      for (int d = 1; d < 64; d <<= 1) {
        x0 |= __shfl_xor(x0, d, 64);
        x1 |= __shfl_xor(x1, d, 64);
      }
      carry0 = x0; carry1 = x1;                  // uniform across lanes
    } else {
      // ---- consume iteration T-1's keeps (published last iteration),
      // fully concurrent with wave0's scan of iteration T.
      if (T > 0) {
        int u = T - 1;
        u64 kws0 = rfl64(keepw[2 * u]);          // broadcast read
        u64 kws1 = rfl64(keepw[2 * u + 1]);
        u64 accL = 0, accH = 0;
        #pragma unroll
        for (int r = 0; r < 19; ++r) {
          int rr = rs + r;                       // wave-uniform
          u64 bit = (rr < 64) ? (kws0 >> rr) : (kws1 >> (rr - 64));
          u64 sm = (u64)0 - (bit & 1ull);
          accL |= tl[r] & sm;
          accH |= th[r] & sm;
        }
        int cL = 2 * u + 4 + lane, cH = cL + 64;
        if (cL < VB) rem7[wave - 1][cL] |= accL; // exclusive cells
        if (cH < VB) rem7[wave - 1][cH] |= accH;
      }
      // refill tiles for iteration T+1 (regs just consumed)
      if (T + 1 < NT) issue_tiles(T);
    }
  }
  __syncthreads();

  // ---- fused masked output (512 threads)
  for (int r2 = tid; r2 < N_ANCH; r2 += 512) {
    u64 kv = keepw[r2 >> 6];
    bool kp = (kv >> (r2 & 63)) & 1ull;
    float4 b4 = sbox[r2];
    float sc = sscore[r2];
    float* o = out + r2 * 5;
    o[0] = kp ? b4.x : 0.f;
    o[1] = kp ? b4.y : 0.f;
    o[2] = kp ? b4.z : 0.f;
    o[3] = kp ? b4.w : 0.f;
    o[4] = kp ? sc : 0.f;
  }
}

extern "C" void kernel_launch(void* const* d_in, const int* in_sizes, int n_in,
                              void* d_out, int out_size, void* d_ws, size_t ws_size,
                              hipStream_t stream) {
  const float* raw = (const float*)d_in[0];
  float* out = (float*)d_out;
  char* ws = (char*)d_ws;
  // ws layout: sbox (8448*16 B) | sscore (8448*4 B) | mask (8400*132*8 B) ≈ 9.04 MB
  float4* sbox = (float4*)ws;
  float* sscore = (float*)(ws + 8448 * 16);
  u64* mask = (u64*)(ws + 8448 * 16 + 8448 * 4);

  rank_kernel<<<2100, 256, 0, stream>>>(raw, sbox, sscore);
  mask_kernel<<<dim3(CBLK, 33), 256, 0, stream>>>(sbox, sscore, mask);
  nms_kernel<<<1, 512, 0, stream>>>(sbox, sscore, mask, out);
}